// Round 6
// baseline (901.816 us; speedup 1.0000x reference)
//
#include <hip/hip_runtime.h>
#include <math.h>

#define LL 2048
#define DD 128
#define NS 16                          // 2 sources * 8 batches
#define SLAB (LL * DD)                 // 262144 fp32 per (src,n)
#define SCALE 0.08838834764831845f     // 1/sqrt(128)

// ---------------------------------------------------------------------------
// Kernel 1: P[ns][l][d] = sum_k x[l][k] * W[d][k] + b[d]   (all fp32)
// block covers 16 l-rows x 64 d (one d-half); grid 16 ns * 128 lblk * 2 dh
// ---------------------------------------------------------------------------
__global__ __launch_bounds__(256) void proj_kernel(
    const float* __restrict__ xt, const float* __restrict__ xf,
    const float* __restrict__ W,  const float* __restrict__ bias,
    float* __restrict__ P)
{
    __shared__ float Wl[64][129];     // 33 KB
    __shared__ float xl[16][129];     // 8.25 KB
    const int blk = blockIdx.x;
    const int ns  = blk >> 8;                 // 256 blocks per (src,n)
    const int r5  = blk & 255;
    const int dh  = r5 & 1;                   // d-half
    const int l0  = (r5 >> 1) << 4;           // 16 rows per block
    const int src = ns >> 3, n = ns & 7;
    const float* x = (src ? xf : xt) + (size_t)(n * LL + l0) * DD;
    const int tid = threadIdx.x;

    for (int t = 0; t < 32; ++t) {            // 64 W-rows x 128 k
        int e = tid + t * 256;
        Wl[e >> 7][e & 127] = W[(size_t)(dh * 64 + (e >> 7)) * DD + (e & 127)];
    }
    for (int t = 0; t < 8; ++t) {             // 16 x-rows x 128 k
        int e = tid + t * 256;
        xl[e >> 7][e & 127] = x[e];
    }
    __syncthreads();

    const int ty = tid >> 4, tx = tid & 15;   // row ty, 4 d-outputs/thread
    float acc[4];
#pragma unroll
    for (int j = 0; j < 4; ++j) acc[j] = bias[dh * 64 + tx + 16 * j];

    for (int k = 0; k < DD; ++k) {
        float xv = xl[ty][k];
#pragma unroll
        for (int j = 0; j < 4; ++j)
            acc[j] = fmaf(xv, Wl[tx + 16 * j][k], acc[j]);
    }
    float* Prow = P + (size_t)ns * SLAB + (size_t)(l0 + ty) * DD + dh * 64;
#pragma unroll
    for (int j = 0; j < 4; ++j) Prow[tx + 16 * j] = acc[j];
}

// ---------------------------------------------------------------------------
// Kernel 2 (phase A): per row l, softmax running max M and denom Z over all m
// 128x128 tiles, BK=32, 8x8 register tile, fp32
// ---------------------------------------------------------------------------
__global__ __launch_bounds__(256) void rowstats_kernel(
    const float* __restrict__ P, float* __restrict__ Mout, float* __restrict__ Zout)
{
    __shared__ float Al[128 * 36];
    __shared__ float Bl[128 * 36];
    const int ns = blockIdx.y;
    const int l0 = blockIdx.x * 128;
    const float* Pb = P + (size_t)ns * SLAB;
    const int tid = threadIdx.x;
    const int ty = tid >> 4, tx = tid & 15;

    float rmax[8], rsum[8];
#pragma unroll
    for (int i = 0; i < 8; ++i) { rmax[i] = -INFINITY; rsum[i] = 0.f; }

    for (int mt = 0; mt < 16; ++mt) {
        const int m0 = mt * 128;
        float acc[8][8];
#pragma unroll
        for (int i = 0; i < 8; ++i)
#pragma unroll
            for (int j = 0; j < 8; ++j) acc[i][j] = 0.f;

        for (int kc = 0; kc < 4; ++kc) {
            __syncthreads();
#pragma unroll
            for (int t = 0; t < 4; ++t) {
                int idx = tid + t * 256;
                int r = idx >> 3, k4 = (idx & 7) << 2;
                *(float4*)&Al[r * 36 + k4] =
                    *(const float4*)&Pb[(size_t)(l0 + r) * DD + kc * 32 + k4];
                *(float4*)&Bl[r * 36 + k4] =
                    *(const float4*)&Pb[(size_t)(m0 + r) * DD + kc * 32 + k4];
            }
            __syncthreads();
#pragma unroll
            for (int k4 = 0; k4 < 32; k4 += 4) {
                float4 a4[8], b4[8];
#pragma unroll
                for (int i = 0; i < 8; ++i) a4[i] = *(const float4*)&Al[(ty + 16 * i) * 36 + k4];
#pragma unroll
                for (int j = 0; j < 8; ++j) b4[j] = *(const float4*)&Bl[(tx + 16 * j) * 36 + k4];
#pragma unroll
                for (int i = 0; i < 8; ++i)
#pragma unroll
                    for (int j = 0; j < 8; ++j) {
                        acc[i][j] = fmaf(a4[i].x, b4[j].x, acc[i][j]);
                        acc[i][j] = fmaf(a4[i].y, b4[j].y, acc[i][j]);
                        acc[i][j] = fmaf(a4[i].z, b4[j].z, acc[i][j]);
                        acc[i][j] = fmaf(a4[i].w, b4[j].w, acc[i][j]);
                    }
            }
        }
#pragma unroll
        for (int i = 0; i < 8; ++i) {
            float s[8], tmax = -INFINITY;
#pragma unroll
            for (int j = 0; j < 8; ++j) { s[j] = acc[i][j] * SCALE; tmax = fmaxf(tmax, s[j]); }
            for (int off = 1; off < 16; off <<= 1) tmax = fmaxf(tmax, __shfl_xor(tmax, off, 64));
            float tsum = 0.f;
#pragma unroll
            for (int j = 0; j < 8; ++j) tsum += expf(s[j] - tmax);
            for (int off = 1; off < 16; off <<= 1) tsum += __shfl_xor(tsum, off, 64);
            float nm = fmaxf(rmax[i], tmax);
            rsum[i] = rsum[i] * expf(rmax[i] - nm) + tsum * expf(tmax - nm);
            rmax[i] = nm;
        }
    }
    if (tx == 0) {
#pragma unroll
        for (int i = 0; i < 8; ++i) {
            int l = l0 + ty + 16 * i;
            Mout[ns * LL + l] = rmax[i];
            Zout[ns * LL + l] = rsum[i];
        }
    }
}

// ---------------------------------------------------------------------------
// Kernel 3 (phase B): score[m] = sum_{l != m} exp(s[l,m]-M_l)/Z_l
// identical FMA sequence to kernel 2 (mul operands commuted only) -> same s
// fp64 score accumulation
// ---------------------------------------------------------------------------
__global__ __launch_bounds__(256) void colsum_kernel(
    const float* __restrict__ P, const float* __restrict__ Mrow,
    const float* __restrict__ Zrow, double* __restrict__ score)
{
    __shared__ float Am[128 * 36];
    __shared__ float Bl[128 * 36];
    __shared__ float mlds[128], izlds[128];
    const int ns = blockIdx.y;
    const int m0 = blockIdx.x * 128;
    const float* Pb = P + (size_t)ns * SLAB;
    const int tid = threadIdx.x;
    const int ty = tid >> 4, tx = tid & 15;

    double sacc[8];
#pragma unroll
    for (int i = 0; i < 8; ++i) sacc[i] = 0.0;

    for (int lt = 0; lt < 16; ++lt) {
        const int l0 = lt * 128;
        float acc[8][8];
#pragma unroll
        for (int i = 0; i < 8; ++i)
#pragma unroll
            for (int j = 0; j < 8; ++j) acc[i][j] = 0.f;

        for (int kc = 0; kc < 4; ++kc) {
            __syncthreads();
#pragma unroll
            for (int t = 0; t < 4; ++t) {
                int idx = tid + t * 256;
                int r = idx >> 3, k4 = (idx & 7) << 2;
                *(float4*)&Am[r * 36 + k4] =
                    *(const float4*)&Pb[(size_t)(m0 + r) * DD + kc * 32 + k4];
                *(float4*)&Bl[r * 36 + k4] =
                    *(const float4*)&Pb[(size_t)(l0 + r) * DD + kc * 32 + k4];
            }
            if (kc == 0 && tid < 128) {
                mlds[tid] = Mrow[ns * LL + l0 + tid];
                izlds[tid] = 1.0f / Zrow[ns * LL + l0 + tid];
            }
            __syncthreads();
#pragma unroll
            for (int k4 = 0; k4 < 32; k4 += 4) {
                float4 a4[8], b4[8];
#pragma unroll
                for (int i = 0; i < 8; ++i) a4[i] = *(const float4*)&Am[(ty + 16 * i) * 36 + k4];
#pragma unroll
                for (int j = 0; j < 8; ++j) b4[j] = *(const float4*)&Bl[(tx + 16 * j) * 36 + k4];
#pragma unroll
                for (int i = 0; i < 8; ++i)
#pragma unroll
                    for (int j = 0; j < 8; ++j) {
                        acc[i][j] = fmaf(a4[i].x, b4[j].x, acc[i][j]);
                        acc[i][j] = fmaf(a4[i].y, b4[j].y, acc[i][j]);
                        acc[i][j] = fmaf(a4[i].z, b4[j].z, acc[i][j]);
                        acc[i][j] = fmaf(a4[i].w, b4[j].w, acc[i][j]);
                    }
            }
        }
#pragma unroll
        for (int i = 0; i < 8; ++i) {
            int m = m0 + ty + 16 * i;
#pragma unroll
            for (int j = 0; j < 8; ++j) {
                int cl = tx + 16 * j;
                int l = l0 + cl;
                float s = acc[i][j] * SCALE;
                float p = expf(s - mlds[cl]) * izlds[cl];
                sacc[i] += (l == m) ? 0.0 : (double)p;
            }
        }
    }
#pragma unroll
    for (int i = 0; i < 8; ++i) {
        double v = sacc[i];
        for (int off = 1; off < 16; off <<= 1) v += __shfl_xor(v, off, 64);
        if (tx == 0) score[ns * LL + m0 + ty + 16 * i] = v;
    }
}

// ---------------------------------------------------------------------------
// Kernel 4: exact bottom-k mask via rank counting (fp64 scores).
// mask[i] = #{j: score_j < score_i} < 1024  <=>  score_i <= 1024th-smallest
// ---------------------------------------------------------------------------
__global__ __launch_bounds__(1024) void mask_kernel(
    const double* __restrict__ score, unsigned char* __restrict__ maskbuf)
{
    __shared__ double s[LL];
    const int ns = blockIdx.x;
    const int tid = threadIdx.x;
    s[tid]        = score[ns * LL + tid];
    s[tid + 1024] = score[ns * LL + tid + 1024];
    __syncthreads();
#pragma unroll
    for (int half = 0; half < 2; ++half) {
        int i = tid + half * 1024;
        double si = s[i];
        int cnt = 0;
        for (int j = 0; j < LL; ++j) cnt += (s[j] < si) ? 1 : 0;
        maskbuf[ns * LL + i] = (cnt < 1024) ? 1 : 0;
    }
}

// ---------------------------------------------------------------------------
// Kernel 5: blend, all fp32.
// out0 = mask_t&~mask_f ? 0.5*(xt+xf) : xt ; out1 = mask_f&~mask_t ? ... : xf
// ---------------------------------------------------------------------------
__global__ __launch_bounds__(256) void blend_kernel(
    const float* __restrict__ xt, const float* __restrict__ xf,
    const unsigned char* __restrict__ maskbuf, float* __restrict__ out)
{
    const int idx4 = blockIdx.x * 256 + threadIdx.x;   // 0..524287 float4s
    const size_t q = (size_t)idx4 * 4;                  // element in slab space
    const int row = (int)(q >> 7);                      // n*2048 + l
    const float4 a = *(const float4*)(xt + q);
    const float4 b = *(const float4*)(xf + q);
    const int mt = maskbuf[row] & 1;
    const int mf = maskbuf[16384 + row] & 1;
    const bool ct = mt && !mf;
    const bool cf = mf && !mt;
    float4 av;
    av.x = 0.5f * (a.x + b.x);  av.y = 0.5f * (a.y + b.y);
    av.z = 0.5f * (a.z + b.z);  av.w = 0.5f * (a.w + b.w);
    float4 o0 = ct ? av : a;
    float4 o1 = cf ? av : b;
    *(float4*)(out + q)                   = o0;
    *(float4*)(out + (size_t)2097152 + q) = o1;
}

// ---------------------------------------------------------------------------
extern "C" void kernel_launch(void* const* d_in, const int* in_sizes, int n_in,
                              void* d_out, int out_size, void* d_ws, size_t ws_size,
                              hipStream_t stream)
{
    // Dict order, all fp32 (reference dtypes): x_t, x_f, W, b.
    const float* xt = (const float*)d_in[0];
    const float* xf = (const float*)d_in[1];
    const float* W  = (const float*)d_in[2];
    const float* b  = (const float*)d_in[3];
    float* out = (float*)d_out;

    // d_out = 4,194,304 fp32 = 16,777,216 B = EXACTLY the 16 P slabs.
    // P is dead before blend overwrites d_out. ws holds only stats (~0.7 MB).
    float* P = (float*)d_out;
    float* M = (float*)d_ws;                              // 32768 fp32
    float* Z = M + NS * LL;                               // 32768 fp32
    double* score = (double*)(Z + NS * LL);               // 32768 fp64 (8B-aligned)
    unsigned char* maskbuf = (unsigned char*)(score + NS * LL);   // 32768 B

    proj_kernel<<<4096, 256, 0, stream>>>(xt, xf, W, b, P);
    rowstats_kernel<<<dim3(16, NS), 256, 0, stream>>>(P, M, Z);
    colsum_kernel<<<dim3(16, NS), 256, 0, stream>>>(P, M, Z, score);
    mask_kernel<<<NS, 1024, 0, stream>>>(score, maskbuf);
    blend_kernel<<<2048, 256, 0, stream>>>(xt, xf, maskbuf, out);
}

// Round 7
// 517.510 us; speedup vs baseline: 1.7426x; 1.7426x over previous
//
#include <hip/hip_runtime.h>
#include <math.h>

#define LL 2048
#define DD 128
#define NS 16                          // 2 sources * 8 batches
#define SLAB (LL * DD)                 // 262144 fp32 per (src,n)
#define SCALE 0.08838834764831845f     // 1/sqrt(128)
#define NT 16                          // 128-row tiles per slab
#define NPAIR 136                      // NT*(NT+1)/2 upper-triangle tile pairs

// ---------------------------------------------------------------------------
// Kernel 1: P[ns][l][d] = sum_k x[l][k] * W[d][k] + b[d]   (all fp32)
// ---------------------------------------------------------------------------
__global__ __launch_bounds__(256) void proj_kernel(
    const float* __restrict__ xt, const float* __restrict__ xf,
    const float* __restrict__ W,  const float* __restrict__ bias,
    float* __restrict__ P)
{
    __shared__ float Wl[64][129];
    __shared__ float xl[16][129];
    const int blk = blockIdx.x;
    const int ns  = blk >> 8;
    const int r5  = blk & 255;
    const int dh  = r5 & 1;
    const int l0  = (r5 >> 1) << 4;
    const int src = ns >> 3, n = ns & 7;
    const float* x = (src ? xf : xt) + (size_t)(n * LL + l0) * DD;
    const int tid = threadIdx.x;

    for (int t = 0; t < 32; ++t) {
        int e = tid + t * 256;
        Wl[e >> 7][e & 127] = W[(size_t)(dh * 64 + (e >> 7)) * DD + (e & 127)];
    }
    for (int t = 0; t < 8; ++t) {
        int e = tid + t * 256;
        xl[e >> 7][e & 127] = x[e];
    }
    __syncthreads();

    const int ty = tid >> 4, tx = tid & 15;
    float acc[4];
#pragma unroll
    for (int j = 0; j < 4; ++j) acc[j] = bias[dh * 64 + tx + 16 * j];

    for (int k = 0; k < DD; ++k) {
        float xv = xl[ty][k];
#pragma unroll
        for (int j = 0; j < 4; ++j)
            acc[j] = fmaf(xv, Wl[tx + 16 * j][k], acc[j]);
    }
    float* Prow = P + (size_t)ns * SLAB + (size_t)(l0 + ty) * DD + dh * 64;
#pragma unroll
    for (int j = 0; j < 4; ++j) Prow[tx + 16 * j] = acc[j];
}

// ---------------------------------------------------------------------------
// Pair decode: blockIdx.x in [0,136) -> (ib <= jb) tile pair
// ---------------------------------------------------------------------------
__device__ __forceinline__ void pair_decode(int p, int& ib, int& jb) {
    int i = 0;
    while (p >= NT - i) { p -= NT - i; ++i; }
    ib = i; jb = i + p;
}

// ---------------------------------------------------------------------------
// Kernel 2: per tile-pair (ib,jb): GEMM 128x128, emit per-tile softmax
// partials (max, sum) for rows of BOTH blocks (symmetry: s[l,m]=s[m,l]).
// Mpart/Zpart layout: [(ns*16 + tile)*2048 + row]
// ---------------------------------------------------------------------------
__global__ __launch_bounds__(256) void stats_kernel(
    const float* __restrict__ P, float* __restrict__ Mpart, float* __restrict__ Zpart)
{
    __shared__ float Al[128 * 36];   // also reused as 2x 128x17 scratch
    __shared__ float Bl[128 * 36];
    int ib, jb;  pair_decode(blockIdx.x, ib, jb);
    const int ns = blockIdx.y;
    const float* Pb = P + (size_t)ns * SLAB;
    const int tid = threadIdx.x;
    const int ty = tid >> 4, tx = tid & 15;

    float acc[8][8];
#pragma unroll
    for (int i = 0; i < 8; ++i)
#pragma unroll
        for (int j = 0; j < 8; ++j) acc[i][j] = 0.f;

    for (int kc = 0; kc < 4; ++kc) {
        __syncthreads();
#pragma unroll
        for (int t = 0; t < 4; ++t) {
            int idx = tid + t * 256;
            int r = idx >> 3, k4 = (idx & 7) << 2;
            *(float4*)&Al[r * 36 + k4] =
                *(const float4*)&Pb[(size_t)(ib * 128 + r) * DD + kc * 32 + k4];
            *(float4*)&Bl[r * 36 + k4] =
                *(const float4*)&Pb[(size_t)(jb * 128 + r) * DD + kc * 32 + k4];
        }
        __syncthreads();
#pragma unroll
        for (int k4 = 0; k4 < 32; k4 += 4) {
            float4 a4[8], b4[8];
#pragma unroll
            for (int i = 0; i < 8; ++i) a4[i] = *(const float4*)&Al[(ty + 16 * i) * 36 + k4];
#pragma unroll
            for (int j = 0; j < 8; ++j) b4[j] = *(const float4*)&Bl[(tx + 16 * j) * 36 + k4];
#pragma unroll
            for (int i = 0; i < 8; ++i)
#pragma unroll
                for (int j = 0; j < 8; ++j) {
                    acc[i][j] = fmaf(a4[i].x, b4[j].x, acc[i][j]);
                    acc[i][j] = fmaf(a4[i].y, b4[j].y, acc[i][j]);
                    acc[i][j] = fmaf(a4[i].z, b4[j].z, acc[i][j]);
                    acc[i][j] = fmaf(a4[i].w, b4[j].w, acc[i][j]);
                }
        }
    }

    // direct: stats for rows of block ib over the 128 cols of block jb
#pragma unroll
    for (int i = 0; i < 8; ++i) {
        float s[8], tmax = -INFINITY;
#pragma unroll
        for (int j = 0; j < 8; ++j) { s[j] = acc[i][j] * SCALE; tmax = fmaxf(tmax, s[j]); }
        for (int off = 1; off < 16; off <<= 1) tmax = fmaxf(tmax, __shfl_xor(tmax, off, 64));
        float tsum = 0.f;
#pragma unroll
        for (int j = 0; j < 8; ++j) tsum += expf(s[j] - tmax);
        for (int off = 1; off < 16; off <<= 1) tsum += __shfl_xor(tsum, off, 64);
        if (tx == 0) {
            int idx = (ns * 16 + jb) * LL + ib * 128 + ty + 16 * i;
            Mpart[idx] = tmax;  Zpart[idx] = tsum;
        }
    }

    // transpose: stats for rows of block jb over the 128 cols of block ib
    if (ib != jb) {
        __syncthreads();
        float* Tm = Al;               // 128*17
        float* Ts = Al + 128 * 17;    // 128*17 (total 4352 <= 4608)
#pragma unroll
        for (int j = 0; j < 8; ++j) {
            float tm = -INFINITY;
#pragma unroll
            for (int i = 0; i < 8; ++i) tm = fmaxf(tm, acc[i][j] * SCALE);
            float tsum = 0.f;
#pragma unroll
            for (int i = 0; i < 8; ++i) tsum += expf(acc[i][j] * SCALE - tm);
            Tm[(tx + 16 * j) * 17 + ty] = tm;
            Ts[(tx + 16 * j) * 17 + ty] = tsum;
        }
        __syncthreads();
        if (tid < 128) {
            float M = -INFINITY;
#pragma unroll
            for (int t = 0; t < 16; ++t) M = fmaxf(M, Tm[tid * 17 + t]);
            float S = 0.f;
#pragma unroll
            for (int t = 0; t < 16; ++t) S += expf(Tm[tid * 17 + t] - M) * Ts[tid * 17 + t];
            int idx = (ns * 16 + ib) * LL + jb * 128 + tid;
            Mpart[idx] = M;  Zpart[idx] = S;
        }
    }
}

// ---------------------------------------------------------------------------
// Kernel 3: combine 16 per-tile partials -> M[row], invZ[row]
// ---------------------------------------------------------------------------
__global__ __launch_bounds__(256) void reduce_stats_kernel(
    const float* __restrict__ Mpart, const float* __restrict__ Zpart,
    float* __restrict__ Mfin, float* __restrict__ iZfin)
{
    const int idx = blockIdx.x * 256 + threadIdx.x;   // ns*2048 + l
    const int ns = idx >> 11, l = idx & 2047;
    float M = -INFINITY;
#pragma unroll
    for (int t = 0; t < 16; ++t) M = fmaxf(M, Mpart[(ns * 16 + t) * LL + l]);
    float Z = 0.f;
#pragma unroll
    for (int t = 0; t < 16; ++t)
        Z += expf(Mpart[(ns * 16 + t) * LL + l] - M) * Zpart[(ns * 16 + t) * LL + l];
    Mfin[idx] = M;
    iZfin[idx] = 1.0f / Z;
}

// ---------------------------------------------------------------------------
// Kernel 4: per tile-pair: recompute s (identical FMA order), emit per-tile
// column partial sums for cols of BOTH blocks. Spart: [(ns*2048+m)*16 + tile]
// ---------------------------------------------------------------------------
__global__ __launch_bounds__(256) void colsum_kernel(
    const float* __restrict__ P, const float* __restrict__ Mfin,
    const float* __restrict__ iZfin, float* __restrict__ Spart)
{
    __shared__ float Al[128 * 36];   // reused as 2x 128x17 scratch
    __shared__ float Bl[128 * 36];
    __shared__ float Mi[128], Zi[128], Mj[128], Zj[128];
    int ib, jb;  pair_decode(blockIdx.x, ib, jb);
    const int ns = blockIdx.y;
    const float* Pb = P + (size_t)ns * SLAB;
    const int tid = threadIdx.x;
    const int ty = tid >> 4, tx = tid & 15;

    if (tid < 128) {
        Mi[tid] = Mfin[ns * LL + ib * 128 + tid];
        Zi[tid] = iZfin[ns * LL + ib * 128 + tid];
    } else {
        int t = tid - 128;
        Mj[t] = Mfin[ns * LL + jb * 128 + t];
        Zj[t] = iZfin[ns * LL + jb * 128 + t];
    }

    float acc[8][8];
#pragma unroll
    for (int i = 0; i < 8; ++i)
#pragma unroll
        for (int j = 0; j < 8; ++j) acc[i][j] = 0.f;

    for (int kc = 0; kc < 4; ++kc) {
        __syncthreads();
#pragma unroll
        for (int t = 0; t < 4; ++t) {
            int idx = tid + t * 256;
            int r = idx >> 3, k4 = (idx & 7) << 2;
            *(float4*)&Al[r * 36 + k4] =
                *(const float4*)&Pb[(size_t)(ib * 128 + r) * DD + kc * 32 + k4];
            *(float4*)&Bl[r * 36 + k4] =
                *(const float4*)&Pb[(size_t)(jb * 128 + r) * DD + kc * 32 + k4];
        }
        __syncthreads();
#pragma unroll
        for (int k4 = 0; k4 < 32; k4 += 4) {
            float4 a4[8], b4[8];
#pragma unroll
            for (int i = 0; i < 8; ++i) a4[i] = *(const float4*)&Al[(ty + 16 * i) * 36 + k4];
#pragma unroll
            for (int j = 0; j < 8; ++j) b4[j] = *(const float4*)&Bl[(tx + 16 * j) * 36 + k4];
#pragma unroll
            for (int i = 0; i < 8; ++i)
#pragma unroll
                for (int j = 0; j < 8; ++j) {
                    acc[i][j] = fmaf(a4[i].x, b4[j].x, acc[i][j]);
                    acc[i][j] = fmaf(a4[i].y, b4[j].y, acc[i][j]);
                    acc[i][j] = fmaf(a4[i].z, b4[j].z, acc[i][j]);
                    acc[i][j] = fmaf(a4[i].w, b4[j].w, acc[i][j]);
                }
        }
    }

    __syncthreads();
    float* Dd = Al;               // direct:    [m_local(jb)][ty]  128x17
    float* Tt = Al + 128 * 17;    // transpose: [m_local(ib)][tx]  128x17

    // direct: p[l in ib, m in jb], col-sum over the 8 ri rows of this thread
#pragma unroll
    for (int j = 0; j < 8; ++j) {
        float sum = 0.f;
#pragma unroll
        for (int i = 0; i < 8; ++i) {
            bool diag = (ib == jb) && (ty + 16 * i == tx + 16 * j);
            float p = expf(acc[i][j] * SCALE - Mi[ty + 16 * i]) * Zi[ty + 16 * i];
            sum += diag ? 0.f : p;
        }
        Dd[(tx + 16 * j) * 17 + ty] = sum;
    }
    // transpose: p[l' in jb, m' in ib] = exp(s - M_l')*invZ_l'
    if (ib != jb) {
#pragma unroll
        for (int i = 0; i < 8; ++i) {
            float sum = 0.f;
#pragma unroll
            for (int j = 0; j < 8; ++j)
                sum += expf(acc[i][j] * SCALE - Mj[tx + 16 * j]) * Zj[tx + 16 * j];
            Tt[(ty + 16 * i) * 17 + tx] = sum;
        }
    }
    __syncthreads();
    if (tid < 128) {
        float s = 0.f;
#pragma unroll
        for (int t = 0; t < 16; ++t) s += Dd[tid * 17 + t];
        Spart[((size_t)ns * LL + jb * 128 + tid) * 16 + ib] = s;
        if (ib != jb) {
            float s2 = 0.f;
#pragma unroll
            for (int t = 0; t < 16; ++t) s2 += Tt[tid * 17 + t];
            Spart[((size_t)ns * LL + ib * 128 + tid) * 16 + jb] = s2;
        }
    }
}

// ---------------------------------------------------------------------------
// Kernel 5: score[m] = sum of 16 tile partials (fp64); exact bottom-k mask
// via rank counting: mask[i] = #{j: score_j < score_i} < 1024
// ---------------------------------------------------------------------------
__global__ __launch_bounds__(1024) void mask_kernel(
    const float* __restrict__ Spart, unsigned char* __restrict__ maskbuf)
{
    __shared__ double s[LL];
    const int ns = blockIdx.x;
    const int tid = threadIdx.x;
#pragma unroll
    for (int h = 0; h < 2; ++h) {
        int m = tid + h * 1024;
        const float* sp = Spart + ((size_t)ns * LL + m) * 16;
        double a = 0.0;
#pragma unroll
        for (int t = 0; t < 16; ++t) a += (double)sp[t];
        s[m] = a;
    }
    __syncthreads();
#pragma unroll
    for (int half = 0; half < 2; ++half) {
        int i = tid + half * 1024;
        double si = s[i];
        int cnt = 0;
        for (int j = 0; j < LL; ++j) cnt += (s[j] < si) ? 1 : 0;
        maskbuf[ns * LL + i] = (cnt < 1024) ? 1 : 0;
    }
}

// ---------------------------------------------------------------------------
// Kernel 6: blend, all fp32.
// ---------------------------------------------------------------------------
__global__ __launch_bounds__(256) void blend_kernel(
    const float* __restrict__ xt, const float* __restrict__ xf,
    const unsigned char* __restrict__ maskbuf, float* __restrict__ out)
{
    const int idx4 = blockIdx.x * 256 + threadIdx.x;
    const size_t q = (size_t)idx4 * 4;
    const int row = (int)(q >> 7);
    const float4 a = *(const float4*)(xt + q);
    const float4 b = *(const float4*)(xf + q);
    const int mt = maskbuf[row] & 1;
    const int mf = maskbuf[16384 + row] & 1;
    const bool ct = mt && !mf;
    const bool cf = mf && !mt;
    float4 av;
    av.x = 0.5f * (a.x + b.x);  av.y = 0.5f * (a.y + b.y);
    av.z = 0.5f * (a.z + b.z);  av.w = 0.5f * (a.w + b.w);
    float4 o0 = ct ? av : a;
    float4 o1 = cf ? av : b;
    *(float4*)(out + q)                   = o0;
    *(float4*)(out + (size_t)2097152 + q) = o1;
}

// ---------------------------------------------------------------------------
extern "C" void kernel_launch(void* const* d_in, const int* in_sizes, int n_in,
                              void* d_out, int out_size, void* d_ws, size_t ws_size,
                              hipStream_t stream)
{
    const float* xt = (const float*)d_in[0];
    const float* xf = (const float*)d_in[1];
    const float* W  = (const float*)d_in[2];
    const float* b  = (const float*)d_in[3];
    float* out = (float*)d_out;

    // d_out (16.8 MB) holds all 16 P slabs; dead before blend overwrites it.
    float* P = (float*)d_out;
    float* Mpart = (float*)d_ws;                       // 16*16*2048 = 524288 f
    float* Zpart = Mpart + 16 * 16 * LL;               // 524288 f
    float* Mfin  = Zpart + 16 * 16 * LL;               // 32768 f
    float* iZfin = Mfin + NS * LL;                     // 32768 f
    float* Spart = iZfin + NS * LL;                    // 16*2048*16 = 524288 f
    unsigned char* maskbuf = (unsigned char*)(Spart + (size_t)16 * LL * 16);
    // total ws: (524288*3 + 32768*2) * 4 + 32768 = 6.6 MB

    proj_kernel<<<4096, 256, 0, stream>>>(xt, xf, W, b, P);
    stats_kernel<<<dim3(NPAIR, NS), 256, 0, stream>>>(P, Mpart, Zpart);
    reduce_stats_kernel<<<128, 256, 0, stream>>>(Mpart, Zpart, Mfin, iZfin);
    colsum_kernel<<<dim3(NPAIR, NS), 256, 0, stream>>>(P, Mfin, iZfin, Spart);
    mask_kernel<<<NS, 1024, 0, stream>>>(Spart, maskbuf);
    blend_kernel<<<2048, 256, 0, stream>>>(xt, xf, maskbuf, out);
}

// Round 8
// 267.729 us; speedup vs baseline: 3.3684x; 1.9330x over previous
//
#include <hip/hip_runtime.h>
#include <math.h>

#define LL 2048
#define DD 128
#define NS 16                          // 2 sources * 8 batches
#define SLAB (LL * DD)                 // 262144 elements per (src,n)
#define SCALE 0.08838834764831845f     // 1/sqrt(128)
#define NT 16                          // 128-row tiles per slab
#define NPAIR 136                      // NT*(NT+1)/2 upper-triangle pairs
#define LSTR 40                        // LDS row stride in bf16 (32 + 8 pad)

typedef __attribute__((ext_vector_type(8))) short short8v;   // 8 bf16 (4 VGPR)
typedef __attribute__((ext_vector_type(4))) float float4v;   // MFMA C/D

__device__ __forceinline__ unsigned int f2bf(float f) {   // RNE, low 16 bits
    unsigned int u = __float_as_uint(f);
    u += 0x7fffu + ((u >> 16) & 1u);
    return u >> 16;
}
__device__ __forceinline__ void pair_decode(int p, int& ib, int& jb) {
    int i = 0;
    while (p >= NT - i) { p -= NT - i; ++i; }
    ib = i; jb = i + p;
}

// ---------------------------------------------------------------------------
// Kernel 1: P = x @ W^T + b (fp32 math, bit-identical to R7), output split
// into P_hi/P_lo bf16 (hi = bf16(p), lo = bf16(p - hi)) stored in d_out.
// Block: 128 l-rows x 128 d. Grid: (16 l-tiles, 16 ns).
// ---------------------------------------------------------------------------
__global__ __launch_bounds__(256) void proj_kernel(
    const float* __restrict__ xt, const float* __restrict__ xf,
    const float* __restrict__ W,  const float* __restrict__ bias,
    unsigned short* __restrict__ Ph, unsigned short* __restrict__ Pl)
{
    __shared__ float Alds[128 * 36];
    __shared__ float Blds[128 * 36];
    __shared__ float bs[128];
    const int ns = blockIdx.y;
    const int l0 = blockIdx.x * 128;
    const int src = ns >> 3, n = ns & 7;
    const float* x = (src ? xf : xt) + (size_t)n * LL * DD;
    const int tid = threadIdx.x;
    const int ty = tid >> 4, tx = tid & 15;

    if (tid < 128) bs[tid] = bias[tid];
    __syncthreads();

    float acc[8][8];
#pragma unroll
    for (int i = 0; i < 8; ++i)
#pragma unroll
        for (int j = 0; j < 8; ++j) acc[i][j] = bs[tx + 16 * j];

    for (int kc = 0; kc < 4; ++kc) {
        __syncthreads();
#pragma unroll
        for (int t = 0; t < 4; ++t) {
            int idx = tid + t * 256;
            int r = idx >> 3, k4 = (idx & 7) << 2;
            *(float4*)&Alds[r * 36 + k4] =
                *(const float4*)&x[(size_t)(l0 + r) * DD + kc * 32 + k4];
            *(float4*)&Blds[r * 36 + k4] =
                *(const float4*)&W[(size_t)r * DD + kc * 32 + k4];
        }
        __syncthreads();
#pragma unroll
        for (int k4 = 0; k4 < 32; k4 += 4) {
            float4 a4[8], b4[8];
#pragma unroll
            for (int i = 0; i < 8; ++i) a4[i] = *(const float4*)&Alds[(ty + 16 * i) * 36 + k4];
#pragma unroll
            for (int j = 0; j < 8; ++j) b4[j] = *(const float4*)&Blds[(tx + 16 * j) * 36 + k4];
#pragma unroll
            for (int i = 0; i < 8; ++i)
#pragma unroll
                for (int j = 0; j < 8; ++j) {
                    acc[i][j] = fmaf(a4[i].x, b4[j].x, acc[i][j]);
                    acc[i][j] = fmaf(a4[i].y, b4[j].y, acc[i][j]);
                    acc[i][j] = fmaf(a4[i].z, b4[j].z, acc[i][j]);
                    acc[i][j] = fmaf(a4[i].w, b4[j].w, acc[i][j]);
                }
        }
    }
#pragma unroll
    for (int i = 0; i < 8; ++i) {
        const size_t rowo = (size_t)ns * SLAB + (size_t)(l0 + ty + 16 * i) * DD;
#pragma unroll
        for (int j = 0; j < 8; ++j) {
            float p = acc[i][j];
            unsigned int hb = f2bf(p);
            float hf = __uint_as_float(hb << 16);
            unsigned int lb = f2bf(p - hf);
            Ph[rowo + tx + 16 * j] = (unsigned short)hb;
            Pl[rowo + tx + 16 * j] = (unsigned short)lb;
        }
    }
}

// ---------------------------------------------------------------------------
// MFMA bf16x4 GEMM core: wave computes 32x128 of the 128x128 tile S(ib,jb).
// acc[rt][ct] is a 16x16 C-frag: col = lane&15, row = quad*4 + reg.
// LDS tiles K-chunked (32), row stride 40 bf16 (conflict-free, 8 words/bank).
// ---------------------------------------------------------------------------
__device__ __forceinline__ void mfma_core(
    const unsigned short* __restrict__ Ph, const unsigned short* __restrict__ Pl,
    int ns, int ib, int jb, int tid,
    unsigned short* Ah, unsigned short* Alo, unsigned short* Bh, unsigned short* Blo,
    float4v acc[2][8])
{
    const int lane = tid & 63;
    const int quad = lane >> 4, l16 = lane & 15;
    const int wave = tid >> 6;
    const int arow = wave * 32;
    const unsigned short* sAh = Ph + (size_t)ns * SLAB + (size_t)ib * 128 * DD;
    const unsigned short* sAl = Pl + (size_t)ns * SLAB + (size_t)ib * 128 * DD;
    const unsigned short* sBh = Ph + (size_t)ns * SLAB + (size_t)jb * 128 * DD;
    const unsigned short* sBl = Pl + (size_t)ns * SLAB + (size_t)jb * 128 * DD;

#pragma unroll
    for (int rt = 0; rt < 2; ++rt)
#pragma unroll
        for (int ct = 0; ct < 8; ++ct)
#pragma unroll
            for (int r = 0; r < 4; ++r) acc[rt][ct][r] = 0.f;

    for (int kc = 0; kc < 4; ++kc) {
        __syncthreads();
#pragma unroll
        for (int it = 0; it < 2; ++it) {
            int idx = tid + it * 256;          // 512 16B-chunks per array
            int r = idx >> 2, c4 = idx & 3;
            size_t go = (size_t)r * DD + kc * 32 + c4 * 8;
            int lo = r * LSTR + c4 * 8;
            *(uint4*)&Ah[lo]  = *(const uint4*)&sAh[go];
            *(uint4*)&Alo[lo] = *(const uint4*)&sAl[go];
            *(uint4*)&Bh[lo]  = *(const uint4*)&sBh[go];
            *(uint4*)&Blo[lo] = *(const uint4*)&sBl[go];
        }
        __syncthreads();
        const int kb = quad * 8;               // A: m=lane&15, k=quad*8+j
        short8v bh[8], bl[8];
#pragma unroll
        for (int ct = 0; ct < 8; ++ct) {
            int ba = (ct * 16 + l16) * LSTR + kb;
            bh[ct] = *(const short8v*)&Bh[ba];
            bl[ct] = *(const short8v*)&Blo[ba];
        }
#pragma unroll
        for (int rt = 0; rt < 2; ++rt) {
            int aa = (arow + rt * 16 + l16) * LSTR + kb;
            short8v ah = *(const short8v*)&Ah[aa];
            short8v al = *(const short8v*)&Alo[aa];
#pragma unroll
            for (int ct = 0; ct < 8; ++ct) {
                acc[rt][ct] = __builtin_amdgcn_mfma_f32_16x16x32_bf16(ah, bh[ct], acc[rt][ct], 0, 0, 0);
                acc[rt][ct] = __builtin_amdgcn_mfma_f32_16x16x32_bf16(ah, bl[ct], acc[rt][ct], 0, 0, 0);
                acc[rt][ct] = __builtin_amdgcn_mfma_f32_16x16x32_bf16(al, bh[ct], acc[rt][ct], 0, 0, 0);
                acc[rt][ct] = __builtin_amdgcn_mfma_f32_16x16x32_bf16(al, bl[ct], acc[rt][ct], 0, 0, 0);
            }
        }
    }
}

// ---------------------------------------------------------------------------
// Kernel 2: per tile-pair softmax partials (max,sum) for rows of BOTH blocks.
// Mpart/Zpart: [(ns*16 + tile)*2048 + row]
// ---------------------------------------------------------------------------
__global__ __launch_bounds__(256, 2) void stats_kernel(
    const unsigned short* __restrict__ Ph, const unsigned short* __restrict__ Pl,
    float* __restrict__ Mpart, float* __restrict__ Zpart)
{
    __shared__ unsigned int AhU[2560], AlU[2560], BhU[2560], BlU[2560];  // 40 KB
    int ib, jb;  pair_decode(blockIdx.x, ib, jb);
    const int ns = blockIdx.y;
    const int tid = threadIdx.x;
    const int lane = tid & 63, quad = lane >> 4, l16 = lane & 15, wave = tid >> 6;
    const int arow = wave * 32;

    float4v acc[2][8];
    mfma_core(Ph, Pl, ns, ib, jb, tid,
              (unsigned short*)AhU, (unsigned short*)AlU,
              (unsigned short*)BhU, (unsigned short*)BlU, acc);

    // direct: rows of ib over the 128 cols of jb (row held by quad lanes)
#pragma unroll
    for (int rt = 0; rt < 2; ++rt)
#pragma unroll
        for (int rg = 0; rg < 4; ++rg) {
            float tmax = -INFINITY;
#pragma unroll
            for (int ct = 0; ct < 8; ++ct) tmax = fmaxf(tmax, acc[rt][ct][rg] * SCALE);
            tmax = fmaxf(tmax, __shfl_xor(tmax, 1));
            tmax = fmaxf(tmax, __shfl_xor(tmax, 2));
            tmax = fmaxf(tmax, __shfl_xor(tmax, 4));
            tmax = fmaxf(tmax, __shfl_xor(tmax, 8));
            float tsum = 0.f;
#pragma unroll
            for (int ct = 0; ct < 8; ++ct) tsum += expf(acc[rt][ct][rg] * SCALE - tmax);
            tsum += __shfl_xor(tsum, 1);
            tsum += __shfl_xor(tsum, 2);
            tsum += __shfl_xor(tsum, 4);
            tsum += __shfl_xor(tsum, 8);
            if (l16 == 0) {
                int o = (ns * 16 + jb) * LL + ib * 128 + arow + rt * 16 + quad * 4 + rg;
                Mpart[o] = tmax;  Zpart[o] = tsum;
            }
        }

    // transpose: rows of jb (= cols here) over the 128 rows of ib
    if (ib != jb) {
        float cm[8], cs[8];
#pragma unroll
        for (int ct = 0; ct < 8; ++ct) {
            float pm = -INFINITY;
#pragma unroll
            for (int rt = 0; rt < 2; ++rt)
#pragma unroll
                for (int rg = 0; rg < 4; ++rg) pm = fmaxf(pm, acc[rt][ct][rg] * SCALE);
            float ps = 0.f;
#pragma unroll
            for (int rt = 0; rt < 2; ++rt)
#pragma unroll
                for (int rg = 0; rg < 4; ++rg) ps += expf(acc[rt][ct][rg] * SCALE - pm);
#pragma unroll
            for (int off = 16; off < 64; off <<= 1) {    // merge across quads
                float om = __shfl_xor(pm, off), os = __shfl_xor(ps, off);
                float nm = fmaxf(pm, om);
                ps = ps * expf(pm - nm) + os * expf(om - nm);
                pm = nm;
            }
            cm[ct] = pm;  cs[ct] = ps;
        }
        __syncthreads();                                   // LDS reuse as scratch
        float* scm = (float*)AhU;                          // [128][5]
        float* scs = scm + 128 * 5;
        if (quad == 0) {
#pragma unroll
            for (int ct = 0; ct < 8; ++ct) {
                int col = ct * 16 + l16;
                scm[col * 5 + wave] = cm[ct];
                scs[col * 5 + wave] = cs[ct];
            }
        }
        __syncthreads();
        if (tid < 128) {
            float M = -INFINITY;
#pragma unroll
            for (int w = 0; w < 4; ++w) M = fmaxf(M, scm[tid * 5 + w]);
            float S = 0.f;
#pragma unroll
            for (int w = 0; w < 4; ++w) S += expf(scm[tid * 5 + w] - M) * scs[tid * 5 + w];
            int o = (ns * 16 + ib) * LL + jb * 128 + tid;
            Mpart[o] = M;  Zpart[o] = S;
        }
    }
}

// ---------------------------------------------------------------------------
// Kernel 3: combine 16 per-tile partials -> M[row], invZ[row]
// ---------------------------------------------------------------------------
__global__ __launch_bounds__(256) void reduce_stats_kernel(
    const float* __restrict__ Mpart, const float* __restrict__ Zpart,
    float* __restrict__ Mfin, float* __restrict__ iZfin)
{
    const int idx = blockIdx.x * 256 + threadIdx.x;   // ns*2048 + l
    const int ns = idx >> 11, l = idx & 2047;
    float M = -INFINITY;
#pragma unroll
    for (int t = 0; t < 16; ++t) M = fmaxf(M, Mpart[(ns * 16 + t) * LL + l]);
    float Z = 0.f;
#pragma unroll
    for (int t = 0; t < 16; ++t)
        Z += expf(Mpart[(ns * 16 + t) * LL + l] - M) * Zpart[(ns * 16 + t) * LL + l];
    Mfin[idx] = M;
    iZfin[idx] = 1.0f / Z;
}

// ---------------------------------------------------------------------------
// Kernel 4: recompute s (identical MFMA sequence), emit per-tile column
// partial sums for cols of BOTH blocks. Spart: [(ns*2048+m)*16 + tile]
// ---------------------------------------------------------------------------
__global__ __launch_bounds__(256, 2) void colsum_kernel(
    const unsigned short* __restrict__ Ph, const unsigned short* __restrict__ Pl,
    const float* __restrict__ Mfin, const float* __restrict__ iZfin,
    float* __restrict__ Spart)
{
    __shared__ unsigned int AhU[2560], AlU[2560], BhU[2560], BlU[2560];
    __shared__ float Mi[128], Zi[128], Mj[128], Zj[128];
    int ib, jb;  pair_decode(blockIdx.x, ib, jb);
    const int ns = blockIdx.y;
    const int tid = threadIdx.x;
    const int lane = tid & 63, quad = lane >> 4, l16 = lane & 15, wave = tid >> 6;
    const int arow = wave * 32;

    if (tid < 128) {
        Mi[tid] = Mfin[ns * LL + ib * 128 + tid];
        Zi[tid] = iZfin[ns * LL + ib * 128 + tid];
    } else {
        int t = tid - 128;
        Mj[t] = Mfin[ns * LL + jb * 128 + t];
        Zj[t] = iZfin[ns * LL + jb * 128 + t];
    }
    float4v acc[2][8];
    mfma_core(Ph, Pl, ns, ib, jb, tid,          // first barrier covers Mi/Mj
              (unsigned short*)AhU, (unsigned short*)AlU,
              (unsigned short*)BhU, (unsigned short*)BlU, acc);

    // direct: col sums for cols of jb (sum over rows of ib), diag excluded
    float dsum[8];
#pragma unroll
    for (int ct = 0; ct < 8; ++ct) {
        float s = 0.f;
#pragma unroll
        for (int rt = 0; rt < 2; ++rt)
#pragma unroll
            for (int rg = 0; rg < 4; ++rg) {
                int rl = arow + rt * 16 + quad * 4 + rg;
                float p = expf(acc[rt][ct][rg] * SCALE - Mi[rl]) * Zi[rl];
                bool diag = (ib == jb) && (rl == ct * 16 + l16);
                s += diag ? 0.f : p;
            }
        s += __shfl_xor(s, 16);
        s += __shfl_xor(s, 32);
        dsum[ct] = s;
    }
    // transpose: col sums for cols = rows of ib (sum over rows of jb)
    if (ib != jb) {
#pragma unroll
        for (int rt = 0; rt < 2; ++rt)
#pragma unroll
            for (int rg = 0; rg < 4; ++rg) {
                float s = 0.f;
#pragma unroll
                for (int ct = 0; ct < 8; ++ct) {
                    int cl = ct * 16 + l16;
                    s += expf(acc[rt][ct][rg] * SCALE - Mj[cl]) * Zj[cl];
                }
                s += __shfl_xor(s, 1);
                s += __shfl_xor(s, 2);
                s += __shfl_xor(s, 4);
                s += __shfl_xor(s, 8);
                if (l16 == 0) {
                    int row = arow + rt * 16 + quad * 4 + rg;
                    Spart[((size_t)ns * LL + ib * 128 + row) * 16 + jb] = s;
                }
            }
    }
    __syncthreads();
    float* scr = (float*)AhU;                 // [128][5] cross-wave combine
    if (quad == 0) {
#pragma unroll
        for (int ct = 0; ct < 8; ++ct) scr[(ct * 16 + l16) * 5 + wave] = dsum[ct];
    }
    __syncthreads();
    if (tid < 128) {
        float t = scr[tid * 5] + scr[tid * 5 + 1] + scr[tid * 5 + 2] + scr[tid * 5 + 3];
        Spart[((size_t)ns * LL + jb * 128 + tid) * 16 + ib] = t;
    }
}

// ---------------------------------------------------------------------------
// Kernel 5: score = sum of 16 tile partials (fp64); exact bottom-k mask via
// rank counting: mask[i] = #{j: score_j < score_i} < 1024
// ---------------------------------------------------------------------------
__global__ __launch_bounds__(1024) void mask_kernel(
    const float* __restrict__ Spart, unsigned char* __restrict__ maskbuf)
{
    __shared__ double s[LL];
    const int ns = blockIdx.x;
    const int half = blockIdx.y;
    const int tid = threadIdx.x;
#pragma unroll
    for (int h = 0; h < 2; ++h) {
        int m = tid + h * 1024;
        const float* sp = Spart + ((size_t)ns * LL + m) * 16;
        double a = 0.0;
#pragma unroll
        for (int t = 0; t < 16; ++t) a += (double)sp[t];
        s[m] = a;
    }
    __syncthreads();
    const int i = half * 1024 + tid;
    const double si = s[i];
    int cnt = 0;
    for (int j = 0; j < LL; ++j) cnt += (s[j] < si) ? 1 : 0;
    maskbuf[ns * LL + i] = (cnt < 1024) ? 1 : 0;
}

// ---------------------------------------------------------------------------
// Kernel 6: blend, all fp32.
// ---------------------------------------------------------------------------
__global__ __launch_bounds__(256) void blend_kernel(
    const float* __restrict__ xt, const float* __restrict__ xf,
    const unsigned char* __restrict__ maskbuf, float* __restrict__ out)
{
    const int idx4 = blockIdx.x * 256 + threadIdx.x;
    const size_t q = (size_t)idx4 * 4;
    const int row = (int)(q >> 7);
    const float4 a = *(const float4*)(xt + q);
    const float4 b = *(const float4*)(xf + q);
    const int mt = maskbuf[row] & 1;
    const int mf = maskbuf[16384 + row] & 1;
    const bool ct = mt && !mf;
    const bool cf = mf && !mt;
    float4 av;
    av.x = 0.5f * (a.x + b.x);  av.y = 0.5f * (a.y + b.y);
    av.z = 0.5f * (a.z + b.z);  av.w = 0.5f * (a.w + b.w);
    float4 o0 = ct ? av : a;
    float4 o1 = cf ? av : b;
    *(float4*)(out + q)                   = o0;
    *(float4*)(out + (size_t)2097152 + q) = o1;
}

// ---------------------------------------------------------------------------
extern "C" void kernel_launch(void* const* d_in, const int* in_sizes, int n_in,
                              void* d_out, int out_size, void* d_ws, size_t ws_size,
                              hipStream_t stream)
{
    const float* xt = (const float*)d_in[0];
    const float* xf = (const float*)d_in[1];
    const float* W  = (const float*)d_in[2];
    const float* b  = (const float*)d_in[3];
    float* out = (float*)d_out;

    // d_out (16.8 MB) holds P split: Ph bf16 [0,8.39MB), Pl bf16 [8.39,16.8MB).
    // Both dead before blend overwrites d_out.
    unsigned short* Ph = (unsigned short*)d_out;
    unsigned short* Pl = Ph + (size_t)NS * SLAB;

    float* Mpart = (float*)d_ws;                       // 16*16*2048 = 524288 f
    float* Zpart = Mpart + 16 * 16 * LL;               // 524288 f
    float* Mfin  = Zpart + 16 * 16 * LL;               // 32768 f
    float* iZfin = Mfin + NS * LL;                     // 32768 f
    float* Spart = iZfin + NS * LL;                    // 524288 f
    unsigned char* maskbuf = (unsigned char*)(Spart + (size_t)16 * LL * 16);
    // total ws ~6.6 MB (same as R7)

    proj_kernel<<<dim3(16, NS), 256, 0, stream>>>(xt, xf, W, b, Ph, Pl);
    stats_kernel<<<dim3(NPAIR, NS), 256, 0, stream>>>(Ph, Pl, Mpart, Zpart);
    reduce_stats_kernel<<<128, 256, 0, stream>>>(Mpart, Zpart, Mfin, iZfin);
    colsum_kernel<<<dim3(NPAIR, NS), 256, 0, stream>>>(Ph, Pl, Mfin, iZfin, Spart);
    mask_kernel<<<dim3(NS, 2), 1024, 0, stream>>>(Spart, maskbuf);
    blend_kernel<<<2048, 256, 0, stream>>>(xt, xf, maskbuf, out);
}